// Round 13
// baseline (623.637 us; speedup 1.0000x reference)
//
#include <hip/hip_runtime.h>
#include <hip/hip_bf16.h>

typedef __attribute__((ext_vector_type(8))) short bf16x8;
typedef __attribute__((ext_vector_type(4))) short bf16x4;
typedef __attribute__((ext_vector_type(4))) float f32x4;
typedef __attribute__((ext_vector_type(16))) float f32x16;

#define DEV __device__ __forceinline__

static constexpr int BATCH = 4096;
static constexpr int KDIM  = 3072;   // in_numel
static constexpr int NOUT  = 16384;  // out_numel

DEV unsigned short f2bf(float f) {
  union { float f; unsigned int u; } v; v.f = f;
  unsigned int u = v.u;
  u += 0x7fffu + ((u >> 16) & 1u);   // RNE
  return (unsigned short)(u >> 16);
}

DEV float bf2f(unsigned short h) {
  union { unsigned int u; float f; } v;
  v.u = ((unsigned int)h) << 16;
  return v.f;
}

DEV bf16x4 pk4(float4 v) {
  bf16x4 o;
  o[0] = (short)f2bf(v.x); o[1] = (short)f2bf(v.y);
  o[2] = (short)f2bf(v.z); o[3] = (short)f2bf(v.w);
  return o;
}

// ---- fused: prep_x (blocks 0..4095) + cvt of T (blocks 4096..5119) ----
__global__ __launch_bounds__(256) void prep_cvtT_kernel(
    const float* __restrict__ x, unsigned short* __restrict__ xbf,
    float* __restrict__ nrm,
    const float* __restrict__ T, unsigned short* __restrict__ tbf) {
  __shared__ float red[4];
  const int bid = blockIdx.x;
  const int t = threadIdx.x;
  if (bid < BATCH) {
    const float* row = x + (size_t)bid * KDIM;
    unsigned short* orow = xbf + (size_t)bid * KDIM;
    float ss = 0.f;
#pragma unroll
    for (int i = 0; i < 3; ++i) {
      const int c = i * 256 + t;               // float4 chunk
      float4 v = reinterpret_cast<const float4*>(row)[c];
      ss += v.x * v.x + v.y * v.y + v.z * v.z + v.w * v.w;
      reinterpret_cast<bf16x4*>(orow)[c] = pk4(v);
    }
#pragma unroll
    for (int off = 32; off > 0; off >>= 1) ss += __shfl_down(ss, off, 64);
    if ((t & 63) == 0) red[t >> 6] = ss;
    __syncthreads();
    if (t == 0) nrm[bid] = sqrtf(red[0] + red[1] + red[2] + red[3]);
  } else {
    const int cb = bid - BATCH;                // 0..1023
    const size_t n4 = (size_t)KDIM * KDIM / 4; // 2359296
    const size_t stride = 1024 * 256;
    for (size_t i = (size_t)cb * 256 + t; i < n4; i += stride) {
      float4 v = reinterpret_cast<const float4*>(T)[i];
      reinterpret_cast<bf16x4*>(tbf)[i] = pk4(v);
    }
  }
}

// ---- ye[b] = s*nrm[b] + sum_{i<48} partial[b][i] ----
__global__ __launch_bounds__(256) void finalize_ye_kernel(
    const float* __restrict__ nrm, const float* __restrict__ partial,
    const float* __restrict__ sp, float* __restrict__ ye) {
  const int b = blockIdx.x * blockDim.x + threadIdx.x;
  if (b >= BATCH) return;
  float qv = 0.f;
#pragma unroll
  for (int i = 0; i < 48; ++i) qv += partial[(size_t)b * 48 + i];
  ye[b] = sp[0] * nrm[b] + qv;
}

// ==================================================================
// Shared BK=64 256x256 machinery. 512 thr = 8 waves (2M x 4N);
// LDS 128 KiB = 2buf x {A,B} x 2half; regions via LDSE(BUF,OP,HALF).
// ==================================================================
static constexpr int BK8 = 64;

#define LDSE(BUF, OP, HALF) ((BUF)*32768 + (OP)*16384 + (HALF)*8192)

#define STAGE8(OP, HALF, S, BUF)                                             \
  {                                                                          \
    const unsigned short* gb_ = (OP) ? Bm : A;                               \
    const int gr0_ = ((OP) ? col0 : row0) + (HALF)*128;                      \
    _Pragma("unroll")                                                        \
    for (int j_ = 0; j_ < 2; ++j_) {                                         \
      const int row_ = j_*64 + wid*8 + (lane >> 3);                          \
      const int le_  = ((lane & 7)*8) ^ ((row_ & 7) << 3);                   \
      __builtin_amdgcn_global_load_lds(                                      \
        (const __attribute__((address_space(1))) unsigned int*)(const void*) \
          (gb_ + (size_t)(gr0_ + row_)*KDIM + (S)*BK8 + le_),                \
        (__attribute__((address_space(3))) unsigned int*)(void*)             \
          (lds + LDSE(BUF, OP, HALF) + j_*4096 + wid*512),                   \
        16, 0, 0);                                                           \
    }                                                                        \
  }

#define VMW(N)                                                               \
  asm volatile("s_waitcnt vmcnt(" #N ")" ::: "memory");                      \
  __builtin_amdgcn_sched_barrier(0)

#define BARR __builtin_amdgcn_s_barrier()

#define LGKMW8 asm volatile("s_waitcnt lgkmcnt(8)" ::: "memory")

// -------- 16x16x32 fragment machinery (qform8 control kernel) --------
#define LOADA8(P, QM, DST)                                                   \
  _Pragma("unroll")                                                          \
  for (int mi = 0; mi < 4; ++mi) {                                           \
    const int r_ = wm*64 + mi*16 + (lane & 15);                              \
    const int xv_ = (r_ & 7) << 3;                                           \
    _Pragma("unroll")                                                        \
    for (int ks = 0; ks < 2; ++ks)                                           \
      DST[mi][ks] = *reinterpret_cast<const bf16x8*>(                        \
          lds + LDSE(P, 0, QM) + ((r_*64 + ks*32 + (lane >> 4)*8) ^ xv_));   \
  }

#define LOADB8(P, QN, DST)                                                   \
  _Pragma("unroll")                                                          \
  for (int ni = 0; ni < 2; ++ni) {                                           \
    const int r_ = wn*32 + ni*16 + (lane & 15);                              \
    const int xv_ = (r_ & 7) << 3;                                           \
    _Pragma("unroll")                                                        \
    for (int ks = 0; ks < 2; ++ks)                                           \
      DST[ni][ks] = *reinterpret_cast<const bf16x8*>(                        \
          lds + LDSE(P, 1, QN) + ((r_*64 + ks*32 + (lane >> 4)*8) ^ xv_));   \
  }

#define MMA8(QM, QN, ASRC, BSRC)                                             \
  __builtin_amdgcn_s_setprio(1);                                             \
  _Pragma("unroll")                                                          \
  for (int mi = 0; mi < 4; ++mi)                                             \
    _Pragma("unroll")                                                        \
    for (int ni = 0; ni < 2; ++ni)                                           \
      _Pragma("unroll")                                                      \
      for (int ks = 0; ks < 2; ++ks)                                         \
        acc[(QM)*4 + mi][(QN)*2 + ni] =                                      \
            __builtin_amdgcn_mfma_f32_16x16x32_bf16(                         \
                ASRC[mi][ks], BSRC[ni][ks], acc[(QM)*4 + mi][(QN)*2 + ni],   \
                0, 0, 0);                                                    \
  __builtin_amdgcn_s_setprio(0);

#define TILE8Q(P, T)                                                         \
  LOADA8(P, 0, aft); LOADB8(P, 0, bft0);                                     \
  STAGE8(1, 1, (T)+1, (P)^1);                                                \
  LGKMW8;                                                                    \
  BARR; MMA8(0, 0, aft, bft0); BARR;                                         \
  LOADB8(P, 1, bft1);                                                        \
  STAGE8(1, 0, (T)+1, (P)^1);                                                \
  BARR; MMA8(0, 1, aft, bft1); BARR;                                         \
  LOADA8(P, 1, aft);                                                         \
  STAGE8(0, 0, (T)+2, P);                                                    \
  BARR; MMA8(1, 1, aft, bft1); BARR;                                         \
  STAGE8(0, 1, (T)+2, P);                                                    \
  BARR; MMA8(1, 0, aft, bft0); VMW(4); BARR;

#define PROLOG8Q(T0)                                                         \
  STAGE8(0, 0, (T0), 0); STAGE8(1, 0, (T0), 0);                              \
  STAGE8(0, 1, (T0), 0); STAGE8(1, 1, (T0), 0);                              \
  STAGE8(0, 0, (T0)+1, 1); STAGE8(0, 1, (T0)+1, 1);                          \
  VMW(4);                                                                    \
  BARR;

#define TAIL8Q(TE)                                                           \
  LOADA8(0, 0, aft); LOADB8(0, 0, bft0);                                     \
  STAGE8(1, 1, (TE)+1, 1);                                                   \
  BARR; MMA8(0, 0, aft, bft0); BARR;                                         \
  LOADB8(0, 1, bft1);                                                        \
  STAGE8(1, 0, (TE)+1, 1);                                                   \
  BARR; MMA8(0, 1, aft, bft1); BARR;                                         \
  LOADA8(0, 1, aft);                                                         \
  BARR; MMA8(1, 1, aft, bft1); BARR;                                         \
  MMA8(1, 0, aft, bft0); VMW(0); BARR;                                       \
  LOADA8(1, 0, aft); LOADB8(1, 0, bft0);                                     \
  BARR; MMA8(0, 0, aft, bft0); BARR;                                         \
  LOADB8(1, 1, bft1);                                                        \
  BARR; MMA8(0, 1, aft, bft1); BARR;                                         \
  LOADA8(1, 1, aft);                                                         \
  BARR; MMA8(1, 1, aft, bft1); BARR;                                         \
  MMA8(1, 0, aft, bft0);

// ==================================================================
// ROUND-13 main GEMM: r9's TILE9 schedule (best measured, 370us)
// with 32x32x16 MFMA (ubench 2382 vs 2075 TF; MFMA-pipe/tile
// 2483 -> 2066 cyc; issue count halved). Same LDS layout/swizzle
// (slot-XOR is 8-element granular; bank audit: balanced, 0-conflict),
// same stage/vmcnt ledger, same [12,4,8,0] read phasing, same VGPR
// budget (A 32 + B 32 + acc 128). C/D mapping (m74/m101-verified):
// col=lane&31, row=(reg&3)+8*(reg>>2)+4*(lane>>5).
// Per phase (QM,QN): wave = 2 mtiles(32) x 1 ntile(32) x 4 ks.
// ==================================================================
#define LOADA3(P, QM, DST)                                                   \
  _Pragma("unroll")                                                          \
  for (int mt = 0; mt < 2; ++mt) {                                           \
    const int r_ = wm*64 + mt*32 + (lane & 31);                              \
    const int xv_ = (r_ & 7) << 3;                                           \
    _Pragma("unroll")                                                        \
    for (int ks = 0; ks < 4; ++ks)                                           \
      DST[mt][ks] = *reinterpret_cast<const bf16x8*>(                        \
          lds + LDSE(P, 0, QM) +                                             \
          ((r_*64 + ks*16 + (lane >> 5)*8) ^ xv_));                          \
  }

#define LOADB3(P, QN, DST)                                                   \
  {                                                                          \
    const int r_ = wn*32 + (lane & 31);                                      \
    const int xv_ = (r_ & 7) << 3;                                           \
    _Pragma("unroll")                                                        \
    for (int ks = 0; ks < 4; ++ks)                                           \
      DST[ks] = *reinterpret_cast<const bf16x8*>(                            \
          lds + LDSE(P, 1, QN) +                                             \
          ((r_*64 + ks*16 + (lane >> 5)*8) ^ xv_));                          \
  }

#define MMA3(QM, QN, ASRC, BSRC)                                             \
  __builtin_amdgcn_s_setprio(1);                                             \
  _Pragma("unroll")                                                          \
  for (int mt = 0; mt < 2; ++mt)                                             \
    _Pragma("unroll")                                                        \
    for (int ks = 0; ks < 4; ++ks)                                           \
      acc[(QM)*2 + mt][QN] =                                                 \
          __builtin_amdgcn_mfma_f32_32x32x16_bf16(                           \
              ASRC[mt][ks], BSRC[ks], acc[(QM)*2 + mt][QN], 0, 0, 0);        \
  __builtin_amdgcn_s_setprio(0);

#define TILE33(P, T)                                                         \
  LOADA3(P, 0, aft); LOADB3(P, 0, bft0);                                     \
  STAGE8(1, 1, (T)+1, (P)^1);                                                \
  BARR;                                                                      \
  STAGE8(1, 0, (T)+1, (P)^1);                                                \
  MMA3(0, 0, aft, bft0);                                                     \
  LOADB3(P, 1, bft1);                                                        \
  BARR;                                                                      \
  STAGE8(0, 0, (T)+2, P);                                                    \
  MMA3(0, 1, aft, bft1);                                                     \
  LOADA3(P, 1, aft);                                                         \
  BARR;                                                                      \
  MMA3(1, 1, aft, bft1);                                                     \
  BARR;                                                                      \
  STAGE8(0, 1, (T)+2, P);                                                    \
  MMA3(1, 0, aft, bft0);                                                     \
  VMW(4);                                                                    \
  BARR;

__global__ __launch_bounds__(512) void gemm33_kernel(
    const unsigned short* __restrict__ A,    // Xbf [4096][3072]
    const unsigned short* __restrict__ Bm,   // Mbf [16384][3072]
    const float* __restrict__ ye,
    float* __restrict__ out) {
  __shared__ unsigned short lds[65536];      // 128 KiB
  const int t = threadIdx.x;
  const int lane = t & 63, wid = t >> 6;
  const int wm = wid >> 2, wn = wid & 3;

  // T1 2D-chunk: each XCD owns a 16(by) x 8(bx) column strip, bx-fastest.
  const int bid = blockIdx.x;                // 1024 = 8 XCD x 128
  const int xcd = bid & 7, r = bid >> 3;     // r in [0,128)
  const int by = r >> 3;                     // [0,16)
  const int bx = xcd * 8 + (r & 7);          // [0,64)
  const int row0 = by * 256, col0 = bx * 256;

  f32x16 acc[4][2];
#pragma unroll
  for (int i = 0; i < 4; ++i)
#pragma unroll
    for (int j = 0; j < 2; ++j)
#pragma unroll
      for (int e = 0; e < 16; ++e) acc[i][j][e] = 0.f;

  bf16x8 aft[2][4], bft0[4], bft1[4];

  // prologue (r9 ledger): B1(0),B0(0),A0(0),A1(0) -> buf0; A0(1),A1(1) -> buf1.
  STAGE8(1, 1, 0, 0); STAGE8(1, 0, 0, 0);
  STAGE8(0, 0, 0, 0); STAGE8(0, 1, 0, 0);
  STAGE8(0, 0, 1, 1); STAGE8(0, 1, 1, 1);
  VMW(4);
  BARR;

#pragma unroll 1
  for (int i = 0; i < 23; ++i) {             // tiles 0..45
    const int t0 = 2 * i;
    TILE33(0, t0);
    TILE33(1, t0 + 1);
  }

  // tile 46 (P=0): stages B1(47),B0(47) only; drains with VMW(0).
  LOADA3(0, 0, aft); LOADB3(0, 0, bft0);
  STAGE8(1, 1, 47, 1);
  BARR;
  STAGE8(1, 0, 47, 1);
  MMA3(0, 0, aft, bft0);
  LOADB3(0, 1, bft1);
  BARR;
  MMA3(0, 1, aft, bft1);
  LOADA3(0, 1, aft);
  BARR;
  MMA3(1, 1, aft, bft1);
  BARR;
  MMA3(1, 0, aft, bft0);
  VMW(0);
  BARR;
  // tile 47 (P=1): pure compute
  LOADA3(1, 0, aft); LOADB3(1, 0, bft0);
  BARR;
  MMA3(0, 0, aft, bft0);
  LOADB3(1, 1, bft1);
  BARR;
  MMA3(0, 1, aft, bft1);
  LOADA3(1, 1, aft);
  BARR;
  MMA3(1, 1, aft, bft1);
  BARR;
  MMA3(1, 0, aft, bft0);

  // epilogue: out[b][o] = acc / ye[b]; 32x32 C/D mapping (m74/m101):
  // col=lane&31, row=(rg&3)+8*(rg>>2)+4*(lane>>5)
#pragma unroll
  for (int am = 0; am < 4; ++am) {
#pragma unroll
    for (int rg = 0; rg < 16; ++rg) {
      const int b = row0 + (am >> 1) * 128 + wm * 64 + (am & 1) * 32 +
                    (rg & 3) + 8 * (rg >> 2) + 4 * (lane >> 5);
      const float rr = 1.0f / ye[b];
      float* orow = out + (size_t)b * NOUT + col0 + wn * 32 + (lane & 31);
#pragma unroll
      for (int an = 0; an < 2; ++an)
        orow[an * 128] = acc[am][an][rg] * rr;
    }
  }
}

// ==== qform8 + interleaved M-convert (r11, measured; 16x16 control) ====
#define CVT_EVEN(PT)                                                         \
  if (DOCVT) {                                                               \
    cb0 = Mf4[cvb + (size_t)(((PT)+1)*3    )*512];                           \
    cb1 = Mf4[cvb + (size_t)(((PT)+1)*3 + 1)*512];                           \
    cb2 = Mf4[cvb + (size_t)(((PT)+1)*3 + 2)*512];                           \
    Mb4[cvb + (size_t)((PT)*3    )*512] = pk4(ca0);                          \
    Mb4[cvb + (size_t)((PT)*3 + 1)*512] = pk4(ca1);                          \
    Mb4[cvb + (size_t)((PT)*3 + 2)*512] = pk4(ca2);                          \
  }
#define CVT_ODD(PT)                                                          \
  if (DOCVT) {                                                               \
    ca0 = Mf4[cvb + (size_t)(((PT)+1)*3    )*512];                           \
    ca1 = Mf4[cvb + (size_t)(((PT)+1)*3 + 1)*512];                           \
    if ((PT) != 9) ca2 = Mf4[cvb + (size_t)(((PT)+1)*3 + 2)*512];            \
    Mb4[cvb + (size_t)((PT)*3    )*512] = pk4(cb0);                          \
    Mb4[cvb + (size_t)((PT)*3 + 1)*512] = pk4(cb1);                          \
    Mb4[cvb + (size_t)((PT)*3 + 2)*512] = pk4(cb2);                          \
  }

template <int DOCVT>
__global__ __launch_bounds__(512) void qform8_kernel(
    const unsigned short* __restrict__ A,    // Xbf [4096][3072]
    const unsigned short* __restrict__ Bm,   // Tbf [3072][3072]
    float* __restrict__ partial,             // [4096][48]
    const float* __restrict__ Mf,            // M f32 (cvt source)
    unsigned short* __restrict__ Mbf) {      // Mbf (cvt dest)
  __shared__ unsigned short lds[65536];      // 128 KiB
  const int t = threadIdx.x;
  const int lane = t & 63, wid = t >> 6;
  const int wm = wid >> 2, wn = wid & 3;

  const int bid = blockIdx.x;                // 768 = 8 x 96
  const int wgid = (bid & 7) * 96 + (bid >> 3);
  const int jt = wgid / 64;                  // [0,12)
  const int rem = wgid % 64;
  const int bt = rem >> 2;                   // [0,16)
  const int ks4 = rem & 3;                   // [0,4) K-slice
  const int row0 = bt * 256, col0 = jt * 256;
  const int k0t = ks4 * 12;                  // base K-tile (12 tiles each)

  f32x4 acc[8][4];
#pragma unroll
  for (int i = 0; i < 8; ++i)
#pragma unroll
    for (int j = 0; j < 4; ++j) acc[i][j] = (f32x4){0.f, 0.f, 0.f, 0.f};

  bf16x8 aft[4][2], bft0[2][2], bft1[2][2];

  const float4* Mf4 = reinterpret_cast<const float4*>(Mf);
  bf16x4* Mb4 = reinterpret_cast<bf16x4*>(Mbf);
  const size_t cvb = (size_t)bid * 16384 + t;   // float4 units
  float4 ca0, ca1, ca2, cb0, cb1, cb2;
  if (DOCVT) {
    ca0 = Mf4[cvb];
    ca1 = Mf4[cvb + 512];
    ca2 = Mf4[cvb + 1024];
  }

  PROLOG8Q(k0t);
#pragma unroll 1
  for (int i = 0; i < 5; ++i) {              // rel tiles 0..9
    const int t0 = k0t + 2 * i;
    CVT_EVEN(2 * i);
    TILE8Q(0, t0);
    CVT_ODD(2 * i + 1);
    TILE8Q(1, t0 + 1);
  }
  if (DOCVT) {
    Mb4[cvb + (size_t)(30) * 512] = pk4(ca0);
    Mb4[cvb + (size_t)(31) * 512] = pk4(ca1);
  }
  TAIL8Q(k0t + 10);                          // rel tiles 10,11

  // epilogue: s[b] = sum_col C[b][col]*Xbf[b][col]; reduce lanes then waves
  float* sred = reinterpret_cast<float*>(lds);   // [8][128] floats = 4 KB
#pragma unroll
  for (int am = 0; am < 8; ++am) {
#pragma unroll
    for (int j = 0; j < 4; ++j) {
      const int b = row0 + (am >> 2) * 128 + wm * 64 + (am & 3) * 16 +
                    (lane >> 4) * 4 + j;
      float s = 0.f;
#pragma unroll
      for (int an = 0; an < 4; ++an) {
        const int col = col0 + (an >> 1) * 128 + wn * 32 + (an & 1) * 16 +
                        (lane & 15);
        s += acc[am][an][j] * bf2f(A[(size_t)b * KDIM + col]);
      }
      s += __shfl_xor(s, 1, 64);
      s += __shfl_xor(s, 2, 64);
      s += __shfl_xor(s, 4, 64);
      s += __shfl_xor(s, 8, 64);
      if ((lane & 15) == 0)
        sred[wid * 128 + am * 16 + j * 4 + (lane >> 4)] = s;
    }
  }
  __syncthreads();
  if (t < 256) {
    const int wmI = t >> 7, idx = t & 127;
    const int am = idx >> 4, j = (idx >> 2) & 3, lp = idx & 3;
    const int b = row0 + (am >> 2) * 128 + wmI * 64 + (am & 3) * 16 + lp * 4 + j;
    float s = 0.f;
#pragma unroll
    for (int w2 = 0; w2 < 4; ++w2) s += sred[(wmI * 4 + w2) * 128 + idx];
    partial[(size_t)b * 48 + jt * 4 + ks4] = s;
  }
}

// ==== fallback main GEMM (ws too small for Mbf): verified 128^2 path ====
__global__ __launch_bounds__(256) void main_gemm_kernel(
    const unsigned short* __restrict__ A,    // Xbf [4096][3072]
    const float* __restrict__ Bf,            // M f32
    const float* __restrict__ ye,
    float* __restrict__ out) {
  __shared__ unsigned short ldsA[128 * 32];
  __shared__ unsigned short ldsB[128 * 32];
  const int t = threadIdx.x;
  const int lane = t & 63;
  const int wv = t >> 6;
  const int wr = wv >> 1, wc = wv & 1;
  const int col0 = blockIdx.x * 128;
  const int row0 = blockIdx.y * 128;

  f32x4 acc[4][4];
#pragma unroll
  for (int i = 0; i < 4; ++i)
#pragma unroll
    for (int j = 0; j < 4; ++j) acc[i][j] = (f32x4){0.f, 0.f, 0.f, 0.f};

  const unsigned short* aBase = A + (size_t)row0 * KDIM;
  const float* bfBase = Bf + (size_t)col0 * KDIM;
  const int ldsoff0 = (t & ~63) * 8;

  for (int k0 = 0; k0 < KDIM; k0 += 32) {
    __syncthreads();
#pragma unroll
    for (int i = 0; i < 2; ++i) {
      const int c = i * 256 + t;
      const unsigned short* ga = aBase + (size_t)(c >> 2) * KDIM + (k0 + (c & 3) * 8);
      __builtin_amdgcn_global_load_lds(
          (const __attribute__((address_space(1))) unsigned int*)(const void*)ga,
          (__attribute__((address_space(3))) unsigned int*)(void*)(ldsA + i * 2048 + ldsoff0),
          16, 0, 0);
    }
#pragma unroll
    for (int i = 0; i < 2; ++i) {
      const int c = i * 256 + t;
      const int r = c >> 1, ko = (c & 1) * 16;
      const float* gp = bfBase + (size_t)r * KDIM + k0 + ko;
      unsigned short tmp[16];
#pragma unroll
      for (int q = 0; q < 4; ++q) {
        float4 v = reinterpret_cast<const float4*>(gp)[q];
        tmp[q * 4 + 0] = f2bf(v.x); tmp[q * 4 + 1] = f2bf(v.y);
        tmp[q * 4 + 2] = f2bf(v.z); tmp[q * 4 + 3] = f2bf(v.w);
      }
#pragma unroll
      for (int q = 0; q < 2; ++q)
        *reinterpret_cast<bf16x8*>(&ldsB[r * 32 + ko + q * 8]) =
            *reinterpret_cast<const bf16x8*>(&tmp[q * 8]);
    }
    __syncthreads();
    bf16x8 af[4], bfr[4];
#pragma unroll
    for (int mi = 0; mi < 4; ++mi)
      af[mi] = *reinterpret_cast<const bf16x8*>(
          &ldsA[(wr * 64 + mi * 16 + (lane & 15)) * 32 + (lane >> 4) * 8]);
#pragma unroll
    for (int ni = 0; ni < 4; ++ni)
      bfr[ni] = *reinterpret_cast<const bf16x8*>(
          &ldsB[(wc * 64 + ni * 16 + (lane & 15)) * 32 + (lane >> 4) * 8]);
#pragma unroll
    for (int mi = 0; mi < 4; ++mi)
#pragma unroll
      for (int ni = 0; ni < 4; ++ni)
        acc[mi][ni] = __builtin_amdgcn_mfma_f32_16x16x32_bf16(af[mi], bfr[ni], acc[mi][ni], 0, 0, 0);
  }

#pragma unroll
  for (int mi = 0; mi < 4; ++mi) {
#pragma unroll
    for (int j = 0; j < 4; ++j) {
      const int b = row0 + wr * 64 + mi * 16 + (lane >> 4) * 4 + j;
      const float rr = 1.0f / ye[b];
      float* orow = out + (size_t)b * NOUT + col0 + wc * 64 + (lane & 15);
#pragma unroll
      for (int ni = 0; ni < 4; ++ni) orow[ni * 16] = acc[mi][ni][j] * rr;
    }
  }
}

extern "C" void kernel_launch(void* const* d_in, const int* in_sizes, int n_in,
                              void* d_out, int out_size, void* d_ws, size_t ws_size,
                              hipStream_t stream) {
  (void)in_sizes; (void)n_in; (void)out_size;
  const float* x  = (const float*)d_in[0];   // [4096][3072]
  const float* M  = (const float*)d_in[1];   // [16384][3072]
  const float* sc = (const float*)d_in[2];   // [1]
  const float* T  = (const float*)d_in[3];   // [3072][3072]
  float* out = (float*)d_out;
  char* ws = (char*)d_ws;

  size_t off = 0;
  auto wsalloc = [&](size_t bytes) -> void* {
    void* p = ws + off;
    off += (bytes + 255) & ~(size_t)255;
    return p;
  };
  unsigned short* Xbf = (unsigned short*)wsalloc((size_t)BATCH * KDIM * 2);
  unsigned short* Tbf = (unsigned short*)wsalloc((size_t)KDIM * KDIM * 2);
  float* nrm = (float*)wsalloc((size_t)BATCH * 4);
  float* ye  = (float*)wsalloc((size_t)BATCH * 4);
  float* partial = (float*)wsalloc((size_t)BATCH * 48 * 4);
  unsigned short* Mbf = (unsigned short*)wsalloc((size_t)NOUT * KDIM * 2);
  const bool useMbf = (off <= ws_size);

  prep_cvtT_kernel<<<BATCH + 1024, 256, 0, stream>>>(x, Xbf, nrm, T, Tbf);
  if (useMbf)
    qform8_kernel<1><<<768, 512, 0, stream>>>(Xbf, Tbf, partial, M, Mbf);
  else
    qform8_kernel<0><<<768, 512, 0, stream>>>(Xbf, Tbf, partial, M, Mbf);
  finalize_ye_kernel<<<BATCH / 256, 256, 0, stream>>>(nrm, partial, sc, ye);
  if (useMbf)
    gemm33_kernel<<<1024, 512, 0, stream>>>(Xbf, Mbf, ye, out);
  else
    main_gemm_kernel<<<dim3(NOUT / 128, BATCH / 128), 256, 0, stream>>>(
        Xbf, M, ye, out);
}

// Round 14
// 551.057 us; speedup vs baseline: 1.1317x; 1.1317x over previous
//
#include <hip/hip_runtime.h>
#include <hip/hip_bf16.h>

typedef __attribute__((ext_vector_type(8))) short bf16x8;
typedef __attribute__((ext_vector_type(4))) short bf16x4;
typedef __attribute__((ext_vector_type(4))) float f32x4;

#define DEV __device__ __forceinline__

static constexpr int BATCH = 4096;
static constexpr int KDIM  = 3072;   // in_numel
static constexpr int NOUT  = 16384;  // out_numel

DEV unsigned short f2bf(float f) {
  union { float f; unsigned int u; } v; v.f = f;
  unsigned int u = v.u;
  u += 0x7fffu + ((u >> 16) & 1u);   // RNE
  return (unsigned short)(u >> 16);
}

DEV float bf2f(unsigned short h) {
  union { unsigned int u; float f; } v;
  v.u = ((unsigned int)h) << 16;
  return v.f;
}

// ---- prep_x: x f32 [4096][3072] -> Xbf bf16; nrm[b] = ||x_b||_2 (f32 exact) ----
__global__ __launch_bounds__(256) void prep_x_kernel(
    const float* __restrict__ x, unsigned short* __restrict__ xbf,
    float* __restrict__ nrm) {
  const int b = blockIdx.x;
  const int t = threadIdx.x;
  const float* row = x + (size_t)b * KDIM;
  unsigned short* orow = xbf + (size_t)b * KDIM;
  float ss = 0.f;
#pragma unroll
  for (int i = 0; i < 3; ++i) {
    const int c = i * 256 + t;                 // float4 chunk
    float4 v = reinterpret_cast<const float4*>(row)[c];
    ss += v.x * v.x + v.y * v.y + v.z * v.z + v.w * v.w;
    bf16x4 o;
    o[0] = (short)f2bf(v.x); o[1] = (short)f2bf(v.y);
    o[2] = (short)f2bf(v.z); o[3] = (short)f2bf(v.w);
    reinterpret_cast<bf16x4*>(orow)[c] = o;
  }
#pragma unroll
  for (int off = 32; off > 0; off >>= 1) ss += __shfl_down(ss, off, 64);
  __shared__ float red[4];
  if ((t & 63) == 0) red[t >> 6] = ss;
  __syncthreads();
  if (t == 0) nrm[b] = sqrtf(red[0] + red[1] + red[2] + red[3]);
}

// ---- generic f32 -> bf16 converter (vectorized, grid-stride) ----
__global__ __launch_bounds__(256) void cvt_kernel(
    const float* __restrict__ src, unsigned short* __restrict__ dst, size_t n4) {
  size_t i = (size_t)blockIdx.x * blockDim.x + threadIdx.x;
  const size_t stride = (size_t)gridDim.x * blockDim.x;
  for (; i < n4; i += stride) {
    float4 v = reinterpret_cast<const float4*>(src)[i];
    bf16x4 o;
    o[0] = (short)f2bf(v.x); o[1] = (short)f2bf(v.y);
    o[2] = (short)f2bf(v.z); o[3] = (short)f2bf(v.w);
    reinterpret_cast<bf16x4*>(dst)[i] = o;
  }
}

// ---- ye[b] = s*nrm[b] + sum_{i<48} partial[b][i] ----
__global__ __launch_bounds__(256) void finalize_ye_kernel(
    const float* __restrict__ nrm, const float* __restrict__ partial,
    const float* __restrict__ sp, float* __restrict__ ye) {
  const int b = blockIdx.x * blockDim.x + threadIdx.x;
  if (b >= BATCH) return;
  float qv = 0.f;
#pragma unroll
  for (int i = 0; i < 48; ++i) qv += partial[(size_t)b * 48 + i];
  ye[b] = sp[0] * nrm[b] + qv;
}

// ==================================================================
// Shared 8-phase 256x256 machinery (r9, best measured). 512 thr = 8 waves
// (2M x 4N); BK=64; LDS 128 KiB = 2buf x {A,B} x 2half.
// Regions: A0=(0,0) A1=(0,1) B0=(1,0) B1=(1,1) via LDSE(BUF,OP,HALF).
// ==================================================================
static constexpr int BK8 = 64;

#define LDSE(BUF, OP, HALF) ((BUF)*32768 + (OP)*16384 + (HALF)*8192)

#define STAGE8(OP, HALF, S, BUF)                                             \
  {                                                                          \
    const unsigned short* gb_ = (OP) ? Bm : A;                               \
    const int gr0_ = ((OP) ? col0 : row0) + (HALF)*128;                      \
    _Pragma("unroll")                                                        \
    for (int j_ = 0; j_ < 2; ++j_) {                                         \
      const int row_ = j_*64 + wid*8 + (lane >> 3);                          \
      const int le_  = ((lane & 7)*8) ^ ((row_ & 7) << 3);                   \
      __builtin_amdgcn_global_load_lds(                                      \
        (const __attribute__((address_space(1))) unsigned int*)(const void*) \
          (gb_ + (size_t)(gr0_ + row_)*KDIM + (S)*BK8 + le_),                \
        (__attribute__((address_space(3))) unsigned int*)(void*)             \
          (lds + LDSE(BUF, OP, HALF) + j_*4096 + wid*512),                   \
        16, 0, 0);                                                           \
    }                                                                        \
  }

#define LOADA8(P, QM, DST)                                                   \
  _Pragma("unroll")                                                          \
  for (int mi = 0; mi < 4; ++mi) {                                           \
    const int r_ = wm*64 + mi*16 + (lane & 15);                              \
    const int xv_ = (r_ & 7) << 3;                                           \
    _Pragma("unroll")                                                        \
    for (int ks = 0; ks < 2; ++ks)                                           \
      DST[mi][ks] = *reinterpret_cast<const bf16x8*>(                        \
          lds + LDSE(P, 0, QM) + ((r_*64 + ks*32 + (lane >> 4)*8) ^ xv_));   \
  }

#define LOADB8(P, QN, DST)                                                   \
  _Pragma("unroll")                                                          \
  for (int ni = 0; ni < 2; ++ni) {                                           \
    const int r_ = wn*32 + ni*16 + (lane & 15);                              \
    const int xv_ = (r_ & 7) << 3;                                           \
    _Pragma("unroll")                                                        \
    for (int ks = 0; ks < 2; ++ks)                                           \
      DST[ni][ks] = *reinterpret_cast<const bf16x8*>(                        \
          lds + LDSE(P, 1, QN) + ((r_*64 + ks*32 + (lane >> 4)*8) ^ xv_));   \
  }

#define MMA8(QM, QN, ASRC, BSRC)                                             \
  __builtin_amdgcn_s_setprio(1);                                             \
  _Pragma("unroll")                                                          \
  for (int mi = 0; mi < 4; ++mi)                                             \
    _Pragma("unroll")                                                        \
    for (int ni = 0; ni < 2; ++ni)                                           \
      _Pragma("unroll")                                                      \
      for (int ks = 0; ks < 2; ++ks)                                         \
        acc[(QM)*4 + mi][(QN)*2 + ni] =                                      \
            __builtin_amdgcn_mfma_f32_16x16x32_bf16(                         \
                ASRC[mi][ks], BSRC[ni][ks], acc[(QM)*4 + mi][(QN)*2 + ni],   \
                0, 0, 0);                                                    \
  __builtin_amdgcn_s_setprio(0);

#define VMW(N)                                                               \
  asm volatile("s_waitcnt vmcnt(" #N ")" ::: "memory");                      \
  __builtin_amdgcn_sched_barrier(0)

#define BARR __builtin_amdgcn_s_barrier()

// -------- ROUND-9 tile: post-MFMA reads, spill-free (12 frag sets).
// Intervals (5 barriers/tile):
//  pre: read A0(t),B0(t); stage B1(t+1)->P^1
//  ph1: stage B0(t+1);  MMA(0,0); read B1(t)
//  ph2: stage A0(t+2)->P; MMA(0,1); read A1(t)->aft
//  ph3: MMA(1,1)
//  ph4: stage A1(t+2)->P; MMA(1,0); VMW(4)
// FIFO ledger at VMW(4): leaves exactly A(t+2)x4; B(t+1)/A(t+1) drained.
#define TILE9(P, T)                                                          \
  LOADA8(P, 0, aft); LOADB8(P, 0, bft0);                                     \
  STAGE8(1, 1, (T)+1, (P)^1);                                                \
  BARR;                                                                      \
  STAGE8(1, 0, (T)+1, (P)^1);                                                \
  MMA8(0, 0, aft, bft0);                                                     \
  LOADB8(P, 1, bft1);                                                        \
  BARR;                                                                      \
  STAGE8(0, 0, (T)+2, P);                                                    \
  MMA8(0, 1, aft, bft1);                                                     \
  LOADA8(P, 1, aft);                                                         \
  BARR;                                                                      \
  MMA8(1, 1, aft, bft1);                                                     \
  BARR;                                                                      \
  STAGE8(0, 1, (T)+2, P);                                                    \
  MMA8(1, 0, aft, bft0);                                                     \
  VMW(4);                                                                    \
  BARR;

// prologue: B1(T0),B0(T0),A0(T0),A1(T0) -> buf0; A0(T0+1),A1(T0+1) -> buf1.
// VMW(4) drains through A1(T0); A(T0+1) stays in flight.
#define PROLOG9(T0)                                                          \
  STAGE8(1, 1, (T0), 0); STAGE8(1, 0, (T0), 0);                              \
  STAGE8(0, 0, (T0), 0); STAGE8(0, 1, (T0), 0);                              \
  STAGE8(0, 0, (T0)+1, 1); STAGE8(0, 1, (T0)+1, 1);                          \
  VMW(4);                                                                    \
  BARR;

// tail: tile TE (P=0, buf0) stages B1(TE+1),B0(TE+1)->buf1, drains VMW(0);
// tile TE+1 (P=1, buf1) pure compute.  (TE even.)
#define TAIL9(TE)                                                            \
  LOADA8(0, 0, aft); LOADB8(0, 0, bft0);                                     \
  STAGE8(1, 1, (TE)+1, 1);                                                   \
  BARR;                                                                      \
  STAGE8(1, 0, (TE)+1, 1);                                                   \
  MMA8(0, 0, aft, bft0);                                                     \
  LOADB8(0, 1, bft1);                                                        \
  BARR;                                                                      \
  MMA8(0, 1, aft, bft1);                                                     \
  LOADA8(0, 1, aft);                                                         \
  BARR;                                                                      \
  MMA8(1, 1, aft, bft1);                                                     \
  BARR;                                                                      \
  MMA8(1, 0, aft, bft0);                                                     \
  VMW(0);                                                                    \
  BARR;                                                                      \
  LOADA8(1, 0, aft); LOADB8(1, 0, bft0);                                     \
  BARR;                                                                      \
  MMA8(0, 0, aft, bft0);                                                     \
  LOADB8(1, 1, bft1);                                                        \
  BARR;                                                                      \
  MMA8(0, 1, aft, bft1);                                                     \
  LOADA8(1, 1, aft);                                                         \
  BARR;                                                                      \
  MMA8(1, 1, aft, bft1);                                                     \
  BARR;                                                                      \
  MMA8(1, 0, aft, bft0);

// ==== main GEMM (round-9 best): out[b][o] = (sum_k Xbf[b][k]*Mbf[o][k]) / ye[b]
__global__ __launch_bounds__(512) void gemm8_kernel(
    const unsigned short* __restrict__ A,    // Xbf [4096][3072]
    const unsigned short* __restrict__ Bm,   // Mbf [16384][3072]
    const float* __restrict__ ye,
    float* __restrict__ out) {
  __shared__ unsigned short lds[65536];      // 128 KiB
  const int t = threadIdx.x;
  const int lane = t & 63, wid = t >> 6;
  const int wm = wid >> 2, wn = wid & 3;

  // T1 2D-chunk: each XCD owns a 16(by) x 8(bx) column strip, bx-fastest.
  const int bid = blockIdx.x;                // 1024 = 8 XCD x 128
  const int xcd = bid & 7, r = bid >> 3;     // r in [0,128)
  const int by = r >> 3;                     // [0,16)
  const int bx = xcd * 8 + (r & 7);          // [0,64)
  const int row0 = by * 256, col0 = bx * 256;

  f32x4 acc[8][4];
#pragma unroll
  for (int i = 0; i < 8; ++i)
#pragma unroll
    for (int j = 0; j < 4; ++j) acc[i][j] = (f32x4){0.f, 0.f, 0.f, 0.f};

  bf16x8 aft[4][2], bft0[2][2], bft1[2][2];

  PROLOG9(0);
#pragma unroll 1
  for (int i = 0; i < 23; ++i) {             // tiles 0..45
    const int t0 = 2 * i;
    TILE9(0, t0);
    TILE9(1, t0 + 1);
  }
  TAIL9(46);                                 // tiles 46,47

  // epilogue: out[b][o] = acc / ye[b]
#pragma unroll
  for (int am = 0; am < 8; ++am) {
#pragma unroll
    for (int j = 0; j < 4; ++j) {
      const int b = row0 + (am >> 2) * 128 + wm * 64 + (am & 3) * 16 +
                    (lane >> 4) * 4 + j;
      const float rr = 1.0f / ye[b];
      float* orow = out + (size_t)b * NOUT + col0;
#pragma unroll
      for (int an = 0; an < 4; ++an)
        orow[(an >> 1) * 128 + wn * 32 + (an & 1) * 16 + (lane & 15)] =
            acc[am][an][j] * rr;
    }
  }
}

// ==== qform8: K-split, r9 TILE9 schedule (was r7 TILE8Q);
// partial[b][jt*4+ks] = sum_j C_ks[b][j]*X[b][j]; grid 768 = 3 blocks/CU.
__global__ __launch_bounds__(512) void qform8_kernel(
    const unsigned short* __restrict__ A,    // Xbf [4096][3072]
    const unsigned short* __restrict__ Bm,   // Tbf [3072][3072]
    float* __restrict__ partial) {           // [4096][48]
  __shared__ unsigned short lds[65536];      // 128 KiB
  const int t = threadIdx.x;
  const int lane = t & 63, wid = t >> 6;
  const int wm = wid >> 2, wn = wid & 3;

  const int bid = blockIdx.x;                // 768 = 8 x 96
  const int wgid = (bid & 7) * 96 + (bid >> 3);
  const int jt = wgid / 64;                  // [0,12)
  const int rem = wgid % 64;
  const int bt = rem >> 2;                   // [0,16)
  const int ks4 = rem & 3;                   // [0,4) K-slice
  const int row0 = bt * 256, col0 = jt * 256;
  const int k0t = ks4 * 12;                  // base K-tile (12 tiles; even)

  f32x4 acc[8][4];
#pragma unroll
  for (int i = 0; i < 8; ++i)
#pragma unroll
    for (int j = 0; j < 4; ++j) acc[i][j] = (f32x4){0.f, 0.f, 0.f, 0.f};

  bf16x8 aft[4][2], bft0[2][2], bft1[2][2];

  PROLOG9(k0t);
#pragma unroll 1
  for (int i = 0; i < 5; ++i) {              // rel tiles 0..9
    const int t0 = k0t + 2 * i;
    TILE9(0, t0);
    TILE9(1, t0 + 1);
  }
  TAIL9(k0t + 10);                           // rel tiles 10,11

  // epilogue: s[b] = sum_col C[b][col]*Xbf[b][col]; reduce lanes then waves
  float* sred = reinterpret_cast<float*>(lds);   // [8][128] floats = 4 KB
#pragma unroll
  for (int am = 0; am < 8; ++am) {
#pragma unroll
    for (int j = 0; j < 4; ++j) {
      const int b = row0 + (am >> 2) * 128 + wm * 64 + (am & 3) * 16 +
                    (lane >> 4) * 4 + j;
      float s = 0.f;
#pragma unroll
      for (int an = 0; an < 4; ++an) {
        const int col = col0 + (an >> 1) * 128 + wn * 32 + (an & 1) * 16 +
                        (lane & 15);
        s += acc[am][an][j] * bf2f(A[(size_t)b * KDIM + col]);
      }
      s += __shfl_xor(s, 1, 64);
      s += __shfl_xor(s, 2, 64);
      s += __shfl_xor(s, 4, 64);
      s += __shfl_xor(s, 8, 64);
      if ((lane & 15) == 0)
        sred[wid * 128 + am * 16 + j * 4 + (lane >> 4)] = s;
    }
  }
  __syncthreads();
  if (t < 256) {
    const int wmI = t >> 7, idx = t & 127;
    const int am = idx >> 4, j = (idx >> 2) & 3, lp = idx & 3;
    const int b = row0 + (am >> 2) * 128 + wmI * 64 + (am & 3) * 16 + lp * 4 + j;
    float s = 0.f;
#pragma unroll
    for (int w2 = 0; w2 < 4; ++w2) s += sred[(wmI * 4 + w2) * 128 + idx];
    partial[(size_t)b * 48 + jt * 4 + ks4] = s;
  }
}

// ==== fallback main GEMM (ws too small for Mbf): verified 128^2 path ====
__global__ __launch_bounds__(256) void main_gemm_kernel(
    const unsigned short* __restrict__ A,    // Xbf [4096][3072]
    const float* __restrict__ Bf,            // M f32
    const float* __restrict__ ye,
    float* __restrict__ out) {
  __shared__ unsigned short ldsA[128 * 32];
  __shared__ unsigned short ldsB[128 * 32];
  const int t = threadIdx.x;
  const int lane = t & 63;
  const int wv = t >> 6;
  const int wr = wv >> 1, wc = wv & 1;
  const int col0 = blockIdx.x * 128;
  const int row0 = blockIdx.y * 128;

  f32x4 acc[4][4];
#pragma unroll
  for (int i = 0; i < 4; ++i)
#pragma unroll
    for (int j = 0; j < 4; ++j) acc[i][j] = (f32x4){0.f, 0.f, 0.f, 0.f};

  const unsigned short* aBase = A + (size_t)row0 * KDIM;
  const float* bfBase = Bf + (size_t)col0 * KDIM;
  const int ldsoff0 = (t & ~63) * 8;

  for (int k0 = 0; k0 < KDIM; k0 += 32) {
    __syncthreads();
#pragma unroll
    for (int i = 0; i < 2; ++i) {
      const int c = i * 256 + t;
      const unsigned short* ga = aBase + (size_t)(c >> 2) * KDIM + (k0 + (c & 3) * 8);
      __builtin_amdgcn_global_load_lds(
          (const __attribute__((address_space(1))) unsigned int*)(const void*)ga,
          (__attribute__((address_space(3))) unsigned int*)(void*)(ldsA + i * 2048 + ldsoff0),
          16, 0, 0);
    }
#pragma unroll
    for (int i = 0; i < 2; ++i) {
      const int c = i * 256 + t;
      const int r = c >> 1, ko = (c & 1) * 16;
      const float* gp = bfBase + (size_t)r * KDIM + k0 + ko;
      unsigned short tmp[16];
#pragma unroll
      for (int q = 0; q < 4; ++q) {
        float4 v = reinterpret_cast<const float4*>(gp)[q];
        tmp[q * 4 + 0] = f2bf(v.x); tmp[q * 4 + 1] = f2bf(v.y);
        tmp[q * 4 + 2] = f2bf(v.z); tmp[q * 4 + 3] = f2bf(v.w);
      }
#pragma unroll
      for (int q = 0; q < 2; ++q)
        *reinterpret_cast<bf16x8*>(&ldsB[r * 32 + ko + q * 8]) =
            *reinterpret_cast<const bf16x8*>(&tmp[q * 8]);
    }
    __syncthreads();
    bf16x8 af[4], bfr[4];
#pragma unroll
    for (int mi = 0; mi < 4; ++mi)
      af[mi] = *reinterpret_cast<const bf16x8*>(
          &ldsA[(wr * 64 + mi * 16 + (lane & 15)) * 32 + (lane >> 4) * 8]);
#pragma unroll
    for (int ni = 0; ni < 4; ++ni)
      bfr[ni] = *reinterpret_cast<const bf16x8*>(
          &ldsB[(wc * 64 + ni * 16 + (lane & 15)) * 32 + (lane >> 4) * 8]);
#pragma unroll
    for (int mi = 0; mi < 4; ++mi)
#pragma unroll
      for (int ni = 0; ni < 4; ++ni)
        acc[mi][ni] = __builtin_amdgcn_mfma_f32_16x16x32_bf16(af[mi], bfr[ni], acc[mi][ni], 0, 0, 0);
  }

#pragma unroll
  for (int mi = 0; mi < 4; ++mi) {
#pragma unroll
    for (int j = 0; j < 4; ++j) {
      const int b = row0 + wr * 64 + mi * 16 + (lane >> 4) * 4 + j;
      const float rr = 1.0f / ye[b];
      float* orow = out + (size_t)b * NOUT + col0 + wc * 64 + (lane & 15);
#pragma unroll
      for (int ni = 0; ni < 4; ++ni) orow[ni * 16] = acc[mi][ni][j] * rr;
    }
  }
}

extern "C" void kernel_launch(void* const* d_in, const int* in_sizes, int n_in,
                              void* d_out, int out_size, void* d_ws, size_t ws_size,
                              hipStream_t stream) {
  (void)in_sizes; (void)n_in; (void)out_size;
  const float* x  = (const float*)d_in[0];   // [4096][3072]
  const float* M  = (const float*)d_in[1];   // [16384][3072]
  const float* sc = (const float*)d_in[2];   // [1]
  const float* T  = (const float*)d_in[3];   // [3072][3072]
  float* out = (float*)d_out;
  char* ws = (char*)d_ws;

  size_t off = 0;
  auto wsalloc = [&](size_t bytes) -> void* {
    void* p = ws + off;
    off += (bytes + 255) & ~(size_t)255;
    return p;
  };
  unsigned short* Xbf = (unsigned short*)wsalloc((size_t)BATCH * KDIM * 2);
  unsigned short* Tbf = (unsigned short*)wsalloc((size_t)KDIM * KDIM * 2);
  float* nrm = (float*)wsalloc((size_t)BATCH * 4);
  float* ye  = (float*)wsalloc((size_t)BATCH * 4);
  float* partial = (float*)wsalloc((size_t)BATCH * 48 * 4);
  unsigned short* Mbf = (unsigned short*)wsalloc((size_t)NOUT * KDIM * 2);
  const bool useMbf = (off <= ws_size);

  prep_x_kernel<<<BATCH, 256, 0, stream>>>(x, Xbf, nrm);
  cvt_kernel<<<1024, 256, 0, stream>>>(T, Tbf, (size_t)KDIM * KDIM / 4);
  if (useMbf)
    cvt_kernel<<<2048, 256, 0, stream>>>(M, Mbf, (size_t)NOUT * KDIM / 4);
  qform8_kernel<<<768, 512, 0, stream>>>(Xbf, Tbf, partial);
  finalize_ye_kernel<<<BATCH / 256, 256, 0, stream>>>(nrm, partial, sc, ye);
  if (useMbf)
    gemm8_kernel<<<1024, 512, 0, stream>>>(Xbf, Mbf, ye, out);
  else
    main_gemm_kernel<<<dim3(NOUT / 128, BATCH / 128), 256, 0, stream>>>(
        Xbf, M, ye, out);
}